// Round 1
// baseline (2094.179 us; speedup 1.0000x reference)
//
#include <hip/hip_runtime.h>

#define T_TOK 4096
#define H_DIM 1024
#define I_DIM 4096
#define E_NUM 8
#define BM 128
#define BN 128
#define BK 32
#define LDK 40  // padded LDS k-stride (bf16 elems): 32 + 8 pad, keeps 16B align

typedef __attribute__((ext_vector_type(8))) short short8;
typedef __attribute__((ext_vector_type(4))) float floatx4;

__device__ __forceinline__ unsigned short f2bf(float f) {
    union { float f; unsigned u; } v; v.f = f;
    unsigned r = v.u + 0x7fffu + ((v.u >> 16) & 1u);  // round-to-nearest-even
    return (unsigned short)(r >> 16);
}

// ---------------- router: logits (fp32), top-2 softmax, expert histogram ----------------
__global__ __launch_bounds__(256) void router_kernel(
    const float* __restrict__ hidden, const float* __restrict__ gate,
    float* __restrict__ logits, int* __restrict__ ws_i,
    int* __restrict__ e0a, int* __restrict__ e1a,
    float* __restrict__ p0a, float* __restrict__ p1a)
{
    int lane = threadIdx.x & 63;
    int t = blockIdx.x * 4 + (threadIdx.x >> 6);
    const float* hrow = hidden + (size_t)t * H_DIM;
    float acc[E_NUM];
#pragma unroll
    for (int e = 0; e < E_NUM; e++) acc[e] = 0.f;
    for (int h = lane; h < H_DIM; h += 64) {
        float x = hrow[h];
        const float4* g = (const float4*)(gate + (size_t)h * E_NUM);
        float4 g0 = g[0], g1 = g[1];
        acc[0] += x * g0.x; acc[1] += x * g0.y; acc[2] += x * g0.z; acc[3] += x * g0.w;
        acc[4] += x * g1.x; acc[5] += x * g1.y; acc[6] += x * g1.z; acc[7] += x * g1.w;
    }
#pragma unroll
    for (int e = 0; e < E_NUM; e++) {
#pragma unroll
        for (int off = 32; off > 0; off >>= 1)
            acc[e] += __shfl_xor(acc[e], off, 64);
    }
    if (lane == 0) {
#pragma unroll
        for (int e = 0; e < E_NUM; e++) logits[(size_t)t * E_NUM + e] = acc[e];
        int e0 = 0;
#pragma unroll
        for (int e = 1; e < E_NUM; e++) if (acc[e] > acc[e0]) e0 = e;   // strict > == first-index tie-break
        int e1 = (e0 == 0) ? 1 : 0;
#pragma unroll
        for (int e = 0; e < E_NUM; e++) if (e != e0 && acc[e] > acc[e1]) e1 = e;
        float z = __expf(acc[e1] - acc[e0]);
        float p0 = 1.f / (1.f + z);
        e0a[t] = e0; e1a[t] = e1; p0a[t] = p0; p1a[t] = 1.f - p0;
        atomicAdd(ws_i + e0, 1);
        atomicAdd(ws_i + e1, 1);
    }
}

// ---------------- prefix sum over 8 experts ----------------
__global__ void prefix_kernel(int* ws_i) {
    if (threadIdx.x == 0) {
        int run = 0;
#pragma unroll
        for (int e = 0; e < E_NUM; e++) {
            ws_i[8 + e] = run;    // base
            ws_i[16 + e] = run;   // cursor
            run += ws_i[e];
        }
    }
}

// ---------------- token->slot assignment + hidden fp32->bf16 ----------------
__global__ __launch_bounds__(256) void assign_cvt_kernel(
    const float* __restrict__ hidden, int* __restrict__ ws_i,
    const int* __restrict__ e0a, const int* __restrict__ e1a,
    const float* __restrict__ p0a, const float* __restrict__ p1a,
    int* __restrict__ token_id, float* __restrict__ tok_w,
    unsigned short* __restrict__ hbf)
{
    int tid = blockIdx.x * 256 + threadIdx.x;
    if (tid < T_TOK) {
        int s0 = atomicAdd(ws_i + 16 + e0a[tid], 1);
        token_id[s0] = tid; tok_w[s0] = p0a[tid];
        int s1 = atomicAdd(ws_i + 16 + e1a[tid], 1);
        token_id[s1] = tid; tok_w[s1] = p1a[tid];
    }
    size_t off = (size_t)tid * 8;
    const float4* src = (const float4*)(hidden + off);
    float4 a = src[0], b = src[1];
    short8 pk;
    pk[0] = (short)f2bf(a.x); pk[1] = (short)f2bf(a.y);
    pk[2] = (short)f2bf(a.z); pk[3] = (short)f2bf(a.w);
    pk[4] = (short)f2bf(b.x); pk[5] = (short)f2bf(b.y);
    pk[6] = (short)f2bf(b.z); pk[7] = (short)f2bf(b.w);
    *(short8*)(hbf + off) = pk;
}

// ---------------- fused up-proj: act = silu(A@w1) * (A@w3), gathered rows ----------------
__global__ __launch_bounds__(256) void up_kernel(
    const float* __restrict__ w1, const float* __restrict__ w3,
    const unsigned short* __restrict__ hbf,
    const int* __restrict__ ws_i, const int* __restrict__ token_id,
    unsigned short* __restrict__ act)
{
    int e = blockIdx.z;
    int n_e = ws_i[e];
    int m0 = blockIdx.y * BM;
    if (m0 >= n_e) return;
    int base_e = ws_i[8 + e];
    int n0 = blockIdx.x * BN;

    __shared__ __align__(16) unsigned short sA[BM * LDK];
    __shared__ __align__(16) unsigned short sB1[BN * LDK];
    __shared__ __align__(16) unsigned short sB3[BN * LDK];

    int tid = threadIdx.x;
    int lane = tid & 63;
    int wv = tid >> 6;
    int wm = (wv >> 1) * 64;
    int wn = (wv & 1) * 64;
    int lr = lane & 15;
    int lq = lane >> 4;

    const float* W1 = w1 + (size_t)e * H_DIM * I_DIM;
    const float* W3 = w3 + (size_t)e * H_DIM * I_DIM;

    floatx4 zero4 = {0.f, 0.f, 0.f, 0.f};
    floatx4 acc1[16], acc3[16];
#pragma unroll
    for (int i = 0; i < 16; i++) { acc1[i] = zero4; acc3[i] = zero4; }

    // A staging tasks: (row, kg); thread handles rows tid>>2 and (tid>>2)+64, kg = tid&3
    int rowA0 = tid >> 2, kgA0 = tid & 3;
    int rowA1 = rowA0 + 64;
    int tA0 = (m0 + rowA0 < n_e) ? token_id[base_e + m0 + rowA0] : -1;
    int tA1 = (m0 + rowA1 < n_e) ? token_id[base_e + m0 + rowA1] : -1;
    // B staging tasks: (n, kg); thread handles n = tid&127, kg = (tid>>7) and (tid>>7)+2
    int nB = tid & 127, kgB = tid >> 7;

    for (int k0 = 0; k0 < H_DIM; k0 += BK) {
        uint4 v0 = {0, 0, 0, 0}, v1 = {0, 0, 0, 0};
        if (tA0 >= 0) v0 = *(const uint4*)(hbf + (size_t)tA0 * H_DIM + k0 + kgA0 * 8);
        if (tA1 >= 0) v1 = *(const uint4*)(hbf + (size_t)tA1 * H_DIM + k0 + kgA0 * 8);
        *(uint4*)(sA + rowA0 * LDK + kgA0 * 8) = v0;
        *(uint4*)(sA + rowA1 * LDK + kgA0 * 8) = v1;
#pragma unroll
        for (int i = 0; i < 2; i++) {
            int kg = kgB + i * 2;
            const float* p1 = W1 + (size_t)(k0 + kg * 8) * I_DIM + (n0 + nB);
            const float* p3 = W3 + (size_t)(k0 + kg * 8) * I_DIM + (n0 + nB);
            short8 b1v, b3v;
#pragma unroll
            for (int j = 0; j < 8; j++) {
                b1v[j] = (short)f2bf(p1[(size_t)j * I_DIM]);
                b3v[j] = (short)f2bf(p3[(size_t)j * I_DIM]);
            }
            *(short8*)(sB1 + nB * LDK + kg * 8) = b1v;
            *(short8*)(sB3 + nB * LDK + kg * 8) = b3v;
        }
        __syncthreads();
        short8 af[4];
#pragma unroll
        for (int mi = 0; mi < 4; mi++)
            af[mi] = *(const short8*)(sA + (wm + mi * 16 + lr) * LDK + lq * 8);
#pragma unroll
        for (int ni = 0; ni < 4; ni++) {
            short8 b1 = *(const short8*)(sB1 + (wn + ni * 16 + lr) * LDK + lq * 8);
            short8 b3 = *(const short8*)(sB3 + (wn + ni * 16 + lr) * LDK + lq * 8);
#pragma unroll
            for (int mi = 0; mi < 4; mi++) {
                acc1[mi * 4 + ni] = __builtin_amdgcn_mfma_f32_16x16x32_bf16(af[mi], b1, acc1[mi * 4 + ni], 0, 0, 0);
                acc3[mi * 4 + ni] = __builtin_amdgcn_mfma_f32_16x16x32_bf16(af[mi], b3, acc3[mi * 4 + ni], 0, 0, 0);
            }
        }
        __syncthreads();
    }
#pragma unroll
    for (int mi = 0; mi < 4; mi++) {
#pragma unroll
        for (int r = 0; r < 4; r++) {
            int gm = m0 + wm + mi * 16 + lq * 4 + r;
            if (gm < n_e) {
                size_t rowoff = (size_t)(base_e + gm) * I_DIM + n0 + wn;
#pragma unroll
                for (int ni = 0; ni < 4; ni++) {
                    float x = acc1[mi * 4 + ni][r];
                    float y = acc3[mi * 4 + ni][r];
                    float s = x / (1.f + __expf(-x)) * y;
                    act[rowoff + ni * 16 + lr] = f2bf(s);
                }
            }
        }
    }
}

// ---------------- down-proj: out[t] += w_t * (act @ w2), scatter via atomics ----------------
__global__ __launch_bounds__(256) void down_kernel(
    const float* __restrict__ w2,
    const unsigned short* __restrict__ act,
    const int* __restrict__ ws_i, const int* __restrict__ token_id,
    const float* __restrict__ tok_w,
    float* __restrict__ out)
{
    int e = blockIdx.z;
    int n_e = ws_i[e];
    int m0 = blockIdx.y * BM;
    if (m0 >= n_e) return;
    int base_e = ws_i[8 + e];
    int n0 = blockIdx.x * BN;

    __shared__ __align__(16) unsigned short sA[BM * LDK];
    __shared__ __align__(16) unsigned short sB[BN * LDK];

    int tid = threadIdx.x;
    int lane = tid & 63;
    int wv = tid >> 6;
    int wm = (wv >> 1) * 64;
    int wn = (wv & 1) * 64;
    int lr = lane & 15;
    int lq = lane >> 4;

    const float* W2 = w2 + (size_t)e * I_DIM * H_DIM;

    floatx4 zero4 = {0.f, 0.f, 0.f, 0.f};
    floatx4 acc[16];
#pragma unroll
    for (int i = 0; i < 16; i++) acc[i] = zero4;

    int rowA0 = tid >> 2, kgA0 = tid & 3;
    int rowA1 = rowA0 + 64;
    bool vA0 = (m0 + rowA0 < n_e), vA1 = (m0 + rowA1 < n_e);
    const unsigned short* arow0 = act + (size_t)(base_e + m0 + rowA0) * I_DIM + kgA0 * 8;
    const unsigned short* arow1 = act + (size_t)(base_e + m0 + rowA1) * I_DIM + kgA0 * 8;
    int nB = tid & 127, kgB = tid >> 7;

    for (int k0 = 0; k0 < I_DIM; k0 += BK) {
        uint4 v0 = {0, 0, 0, 0}, v1 = {0, 0, 0, 0};
        if (vA0) v0 = *(const uint4*)(arow0 + k0);
        if (vA1) v1 = *(const uint4*)(arow1 + k0);
        *(uint4*)(sA + rowA0 * LDK + kgA0 * 8) = v0;
        *(uint4*)(sA + rowA1 * LDK + kgA0 * 8) = v1;
#pragma unroll
        for (int i = 0; i < 2; i++) {
            int kg = kgB + i * 2;
            const float* p = W2 + (size_t)(k0 + kg * 8) * H_DIM + (n0 + nB);
            short8 bv;
#pragma unroll
            for (int j = 0; j < 8; j++) bv[j] = (short)f2bf(p[(size_t)j * H_DIM]);
            *(short8*)(sB + nB * LDK + kg * 8) = bv;
        }
        __syncthreads();
        short8 af[4];
#pragma unroll
        for (int mi = 0; mi < 4; mi++)
            af[mi] = *(const short8*)(sA + (wm + mi * 16 + lr) * LDK + lq * 8);
#pragma unroll
        for (int ni = 0; ni < 4; ni++) {
            short8 b = *(const short8*)(sB + (wn + ni * 16 + lr) * LDK + lq * 8);
#pragma unroll
            for (int mi = 0; mi < 4; mi++)
                acc[mi * 4 + ni] = __builtin_amdgcn_mfma_f32_16x16x32_bf16(af[mi], b, acc[mi * 4 + ni], 0, 0, 0);
        }
        __syncthreads();
    }
#pragma unroll
    for (int mi = 0; mi < 4; mi++) {
#pragma unroll
        for (int r = 0; r < 4; r++) {
            int gm = m0 + wm + mi * 16 + lq * 4 + r;
            if (gm < n_e) {
                int gs = base_e + gm;
                int t = token_id[gs];
                float wgt = tok_w[gs];
                float* orow = out + (size_t)t * H_DIM + n0 + wn;
#pragma unroll
                for (int ni = 0; ni < 4; ni++)
                    atomicAdd(orow + ni * 16 + lr, wgt * acc[mi * 4 + ni][r]);
            }
        }
    }
}

extern "C" void kernel_launch(void* const* d_in, const int* in_sizes, int n_in,
                              void* d_out, int out_size, void* d_ws, size_t ws_size,
                              hipStream_t stream) {
    const float* hidden = (const float*)d_in[0];
    const float* gate   = (const float*)d_in[1];
    const float* w1     = (const float*)d_in[2];
    const float* w3     = (const float*)d_in[3];
    const float* w2     = (const float*)d_in[4];
    float* out_final  = (float*)d_out;
    float* out_logits = out_final + (size_t)T_TOK * H_DIM;

    // workspace layout (~75.6 MB total)
    char* wsb = (char*)d_ws;
    int*   ws_i     = (int*)wsb;                              // counts[8], base[8], cursor[8]
    int*   e0a      = (int*)(wsb + 256);                      // [T]
    int*   e1a      = e0a + T_TOK;
    float* p0a      = (float*)(e1a + T_TOK);
    float* p1a      = p0a + T_TOK;
    int*   token_id = (int*)(p1a + T_TOK);                    // [2T]
    float* tok_w    = (float*)(token_id + 2 * T_TOK);         // [2T]
    unsigned short* hbf = (unsigned short*)(tok_w + 2 * T_TOK);   // [T*H] bf16
    unsigned short* act = hbf + (size_t)T_TOK * H_DIM;            // [2T*I] bf16

    hipMemsetAsync(d_out, 0, (size_t)T_TOK * H_DIM * sizeof(float), stream);
    hipMemsetAsync(d_ws, 0, 256, stream);

    router_kernel<<<T_TOK / 4, 256, 0, stream>>>(hidden, gate, out_logits, ws_i, e0a, e1a, p0a, p1a);
    prefix_kernel<<<1, 64, 0, stream>>>(ws_i);
    assign_cvt_kernel<<<(T_TOK * H_DIM / 8) / 256, 256, 0, stream>>>(
        hidden, ws_i, e0a, e1a, p0a, p1a, token_id, tok_w, hbf);
    up_kernel<<<dim3(I_DIM / BN, T_TOK / BM, E_NUM), 256, 0, stream>>>(
        w1, w3, hbf, ws_i, token_id, act);
    down_kernel<<<dim3(H_DIM / BN, T_TOK / BM, E_NUM), 256, 0, stream>>>(
        w2, act, ws_i, token_id, tok_w, out_final);
}

// Round 2
// 863.513 us; speedup vs baseline: 2.4252x; 2.4252x over previous
//
#include <hip/hip_runtime.h>

#define T_TOK 4096
#define H_DIM 1024
#define I_DIM 4096
#define E_NUM 8

typedef __attribute__((ext_vector_type(8))) short short8;
typedef __attribute__((ext_vector_type(4))) float floatx4;

__device__ __forceinline__ unsigned short f2bf(float f) {
    union { float f; unsigned u; } v; v.f = f;
    unsigned r = v.u + 0x7fffu + ((v.u >> 16) & 1u);  // round-to-nearest-even
    return (unsigned short)(r >> 16);
}

__device__ __forceinline__ void gl_lds16(const unsigned short* g, unsigned short* l) {
    __builtin_amdgcn_global_load_lds((const __attribute__((address_space(1))) void*)g,
                                     (__attribute__((address_space(3))) void*)l, 16, 0, 0);
}

// ---------------- router: logits (fp32), top-2 softmax, expert histogram ----------------
__global__ __launch_bounds__(256) void router_kernel(
    const float* __restrict__ hidden, const float* __restrict__ gate,
    float* __restrict__ logits, int* __restrict__ ws_i,
    int* __restrict__ e0a, int* __restrict__ e1a,
    float* __restrict__ p0a, float* __restrict__ p1a)
{
    int lane = threadIdx.x & 63;
    int t = blockIdx.x * 4 + (threadIdx.x >> 6);
    const float* hrow = hidden + (size_t)t * H_DIM;
    float acc[E_NUM];
#pragma unroll
    for (int e = 0; e < E_NUM; e++) acc[e] = 0.f;
    for (int h = lane; h < H_DIM; h += 64) {
        float x = hrow[h];
        const float4* g = (const float4*)(gate + (size_t)h * E_NUM);
        float4 g0 = g[0], g1 = g[1];
        acc[0] += x * g0.x; acc[1] += x * g0.y; acc[2] += x * g0.z; acc[3] += x * g0.w;
        acc[4] += x * g1.x; acc[5] += x * g1.y; acc[6] += x * g1.z; acc[7] += x * g1.w;
    }
#pragma unroll
    for (int e = 0; e < E_NUM; e++) {
#pragma unroll
        for (int off = 32; off > 0; off >>= 1)
            acc[e] += __shfl_xor(acc[e], off, 64);
    }
    if (lane == 0) {
#pragma unroll
        for (int e = 0; e < E_NUM; e++) logits[(size_t)t * E_NUM + e] = acc[e];
        int e0 = 0;
#pragma unroll
        for (int e = 1; e < E_NUM; e++) if (acc[e] > acc[e0]) e0 = e;   // strict > == first-index tie-break
        int e1 = (e0 == 0) ? 1 : 0;
#pragma unroll
        for (int e = 0; e < E_NUM; e++) if (e != e0 && acc[e] > acc[e1]) e1 = e;
        float z = __expf(acc[e1] - acc[e0]);
        float p0 = 1.f / (1.f + z);
        e0a[t] = e0; e1a[t] = e1; p0a[t] = p0; p1a[t] = 1.f - p0;
        atomicAdd(ws_i + e0, 1);
        atomicAdd(ws_i + e1, 1);
    }
}

// ---------------- prefix sum over 8 experts ----------------
__global__ void prefix_kernel(int* ws_i) {
    if (threadIdx.x == 0) {
        int run = 0;
#pragma unroll
        for (int e = 0; e < E_NUM; e++) {
            ws_i[8 + e] = run;    // base
            ws_i[16 + e] = run;   // cursor
            run += ws_i[e];
        }
    }
}

// ---------------- token->slot assignment + hidden fp32->bf16 ----------------
__global__ __launch_bounds__(256) void assign_cvt_kernel(
    const float* __restrict__ hidden, int* __restrict__ ws_i,
    const int* __restrict__ e0a, const int* __restrict__ e1a,
    const float* __restrict__ p0a, const float* __restrict__ p1a,
    int* __restrict__ token_id, float* __restrict__ tok_w,
    unsigned short* __restrict__ hbf)
{
    int tid = blockIdx.x * 256 + threadIdx.x;
    if (tid < T_TOK) {
        int s0 = atomicAdd(ws_i + 16 + e0a[tid], 1);
        token_id[s0] = tid; tok_w[s0] = p0a[tid];
        int s1 = atomicAdd(ws_i + 16 + e1a[tid], 1);
        token_id[s1] = tid; tok_w[s1] = p1a[tid];
    }
    size_t off = (size_t)tid * 8;
    const float4* src = (const float4*)(hidden + off);
    float4 a = src[0], b = src[1];
    short8 pk;
    pk[0] = (short)f2bf(a.x); pk[1] = (short)f2bf(a.y);
    pk[2] = (short)f2bf(a.z); pk[3] = (short)f2bf(a.w);
    pk[4] = (short)f2bf(b.x); pk[5] = (short)f2bf(b.y);
    pk[6] = (short)f2bf(b.z); pk[7] = (short)f2bf(b.w);
    *(short8*)(hbf + off) = pk;
}

// ---------------- transpose + fp32->bf16 convert: in[e][R][C] -> out[e][C][R] ----------------
__global__ __launch_bounds__(256) void cvt_t_kernel(
    const float* __restrict__ in, unsigned short* __restrict__ out, int R, int C)
{
    __shared__ float tile[64][65];
    int e = blockIdx.z;
    const float* src = in + (size_t)e * R * C;
    unsigned short* dst = out + (size_t)e * R * C;
    int c0 = blockIdx.x * 64, r0 = blockIdx.y * 64;
    int t = threadIdx.x;
    int cc = (t & 15) * 4;
    int rr = t >> 4;
#pragma unroll
    for (int p = 0; p < 4; p++) {
        int r = rr + p * 16;
        float4 v = *(const float4*)(src + (size_t)(r0 + r) * C + c0 + cc);
        tile[r][cc] = v.x; tile[r][cc + 1] = v.y; tile[r][cc + 2] = v.z; tile[r][cc + 3] = v.w;
    }
    __syncthreads();
    int c = t >> 3;
    int rg = (t & 7) * 8;
#pragma unroll
    for (int p = 0; p < 2; p++) {
        int cc2 = c + p * 32;
        short8 pk;
#pragma unroll
        for (int j = 0; j < 8; j++) pk[j] = (short)f2bf(tile[rg + j][cc2]);
        *(short8*)(dst + (size_t)(c0 + cc2) * R + r0 + rg) = pk;
    }
}

// ================= PRIMARY GEMMs: bf16 weights pre-transposed, global_load_lds staging ==========

// fused up-proj: act = silu(A@w1) * (A@w3); BM=128, BN=64, BK=32; 4 waves, wave tile 64x32
__global__ __launch_bounds__(256) void up_kernel(
    const unsigned short* __restrict__ w1t,  // [e][I][H] bf16
    const unsigned short* __restrict__ w3t,
    const unsigned short* __restrict__ hbf,  // [T][H] bf16
    const int* __restrict__ ws_i, const int* __restrict__ token_id,
    unsigned short* __restrict__ act)        // [2T][I] bf16 (slot rows)
{
    int e = blockIdx.z;
    int n_e = ws_i[e];
    int m0 = blockIdx.y * 128;
    if (m0 >= n_e) return;
    int base = ws_i[8 + e];
    int n0 = blockIdx.x * 64;

    __shared__ __align__(16) unsigned short sA[128 * 32];
    __shared__ __align__(16) unsigned short sB1[64 * 32];
    __shared__ __align__(16) unsigned short sB3[64 * 32];

    int tid = threadIdx.x;
    int lane = tid & 63;
    int wv = tid >> 6;
    int wm = (wv & 1) * 64;
    int wn = (wv >> 1) * 32;
    int lr = lane & 15;
    int lq = lane >> 4;

    // staging slot mapping: slot = tid; row = tid>>2, kgroup = tid&3 (8 bf16 each)
    int rowS = tid >> 2, kg = tid & 3;
    int r0 = m0 + rowS;      if (r0 > n_e - 1) r0 = n_e - 1;
    int r1 = m0 + rowS + 64; if (r1 > n_e - 1) r1 = n_e - 1;
    const unsigned short* ga0 = hbf + (size_t)token_id[base + r0] * H_DIM + kg * 8;
    const unsigned short* ga1 = hbf + (size_t)token_id[base + r1] * H_DIM + kg * 8;
    const unsigned short* gb1 = w1t + (size_t)e * I_DIM * H_DIM + (size_t)(n0 + rowS) * H_DIM + kg * 8;
    const unsigned short* gb3 = w3t + (size_t)e * I_DIM * H_DIM + (size_t)(n0 + rowS) * H_DIM + kg * 8;
    unsigned short* lA0 = sA + wv * 512;           // rows 0..63
    unsigned short* lA1 = sA + 2048 + wv * 512;    // rows 64..127
    unsigned short* lB1 = sB1 + wv * 512;
    unsigned short* lB3 = sB3 + wv * 512;

    floatx4 zero4 = {0.f, 0.f, 0.f, 0.f};
    floatx4 acc1[8], acc3[8];
#pragma unroll
    for (int i = 0; i < 8; i++) { acc1[i] = zero4; acc3[i] = zero4; }

    for (int k0 = 0; k0 < H_DIM; k0 += 32) {
        gl_lds16(ga0 + k0, lA0);
        gl_lds16(ga1 + k0, lA1);
        gl_lds16(gb1 + k0, lB1);
        gl_lds16(gb3 + k0, lB3);
        __syncthreads();   // drains vmcnt -> LDS visible
        short8 af[4];
#pragma unroll
        for (int mi = 0; mi < 4; mi++)
            af[mi] = *(const short8*)(sA + (wm + mi * 16 + lr) * 32 + lq * 8);
#pragma unroll
        for (int ni = 0; ni < 2; ni++) {
            short8 b1 = *(const short8*)(sB1 + (wn + ni * 16 + lr) * 32 + lq * 8);
            short8 b3 = *(const short8*)(sB3 + (wn + ni * 16 + lr) * 32 + lq * 8);
#pragma unroll
            for (int mi = 0; mi < 4; mi++) {
                acc1[mi * 2 + ni] = __builtin_amdgcn_mfma_f32_16x16x32_bf16(af[mi], b1, acc1[mi * 2 + ni], 0, 0, 0);
                acc3[mi * 2 + ni] = __builtin_amdgcn_mfma_f32_16x16x32_bf16(af[mi], b3, acc3[mi * 2 + ni], 0, 0, 0);
            }
        }
        __syncthreads();
    }
#pragma unroll
    for (int mi = 0; mi < 4; mi++) {
#pragma unroll
        for (int r = 0; r < 4; r++) {
            int gm = m0 + wm + mi * 16 + lq * 4 + r;
            if (gm < n_e) {
                size_t rowoff = (size_t)(base + gm) * I_DIM + n0 + wn;
#pragma unroll
                for (int ni = 0; ni < 2; ni++) {
                    float x = acc1[mi * 2 + ni][r];
                    float y = acc3[mi * 2 + ni][r];
                    float s = x / (1.f + __expf(-x)) * y;
                    act[rowoff + ni * 16 + lr] = f2bf(s);
                }
            }
        }
    }
}

// down-proj: out[t] += w_t * (act @ w2); BM=128, BN=128, BK=32; 4 waves, wave tile 64x64
__global__ __launch_bounds__(256) void down_kernel(
    const unsigned short* __restrict__ w2t,  // [e][H][I] bf16
    const unsigned short* __restrict__ act,
    const int* __restrict__ ws_i, const int* __restrict__ token_id,
    const float* __restrict__ tok_w,
    float* __restrict__ out)
{
    int e = blockIdx.z;
    int n_e = ws_i[e];
    int m0 = blockIdx.y * 128;
    if (m0 >= n_e) return;
    int base = ws_i[8 + e];
    int n0 = blockIdx.x * 128;

    __shared__ __align__(16) unsigned short sA[128 * 32];
    __shared__ __align__(16) unsigned short sB[128 * 32];

    int tid = threadIdx.x;
    int lane = tid & 63;
    int wv = tid >> 6;
    int wm = (wv >> 1) * 64;
    int wn = (wv & 1) * 64;
    int lr = lane & 15;
    int lq = lane >> 4;

    int rowS = tid >> 2, kg = tid & 3;
    int r0 = m0 + rowS;      if (r0 > n_e - 1) r0 = n_e - 1;
    int r1 = m0 + rowS + 64; if (r1 > n_e - 1) r1 = n_e - 1;
    const unsigned short* ga0 = act + (size_t)(base + r0) * I_DIM + kg * 8;
    const unsigned short* ga1 = act + (size_t)(base + r1) * I_DIM + kg * 8;
    const unsigned short* gb0 = w2t + (size_t)e * H_DIM * I_DIM + (size_t)(n0 + rowS) * I_DIM + kg * 8;
    const unsigned short* gb1 = gb0 + (size_t)64 * I_DIM;
    unsigned short* lA0 = sA + wv * 512;
    unsigned short* lA1 = sA + 2048 + wv * 512;
    unsigned short* lB0 = sB + wv * 512;
    unsigned short* lB1l = sB + 2048 + wv * 512;

    floatx4 zero4 = {0.f, 0.f, 0.f, 0.f};
    floatx4 acc[16];
#pragma unroll
    for (int i = 0; i < 16; i++) acc[i] = zero4;

    for (int k0 = 0; k0 < I_DIM; k0 += 32) {
        gl_lds16(ga0 + k0, lA0);
        gl_lds16(ga1 + k0, lA1);
        gl_lds16(gb0 + k0, lB0);
        gl_lds16(gb1 + k0, lB1l);
        __syncthreads();
        short8 af[4];
#pragma unroll
        for (int mi = 0; mi < 4; mi++)
            af[mi] = *(const short8*)(sA + (wm + mi * 16 + lr) * 32 + lq * 8);
#pragma unroll
        for (int ni = 0; ni < 4; ni++) {
            short8 b = *(const short8*)(sB + (wn + ni * 16 + lr) * 32 + lq * 8);
#pragma unroll
            for (int mi = 0; mi < 4; mi++)
                acc[mi * 4 + ni] = __builtin_amdgcn_mfma_f32_16x16x32_bf16(af[mi], b, acc[mi * 4 + ni], 0, 0, 0);
        }
        __syncthreads();
    }
#pragma unroll
    for (int mi = 0; mi < 4; mi++) {
#pragma unroll
        for (int r = 0; r < 4; r++) {
            int gm = m0 + wm + mi * 16 + lq * 4 + r;
            if (gm < n_e) {
                int gs = base + gm;
                int t = token_id[gs];
                float wgt = tok_w[gs];
                float* orow = out + (size_t)t * H_DIM + n0 + wn;
#pragma unroll
                for (int ni = 0; ni < 4; ni++)
                    atomicAdd(orow + ni * 16 + lr, wgt * acc[mi * 4 + ni][r]);
            }
        }
    }
}

// ================= FALLBACK GEMMs (Round-1, convert-in-kernel) — used only if ws too small =====
#define LDK 40

__global__ __launch_bounds__(256) void up_fb(
    const float* __restrict__ w1, const float* __restrict__ w3,
    const unsigned short* __restrict__ hbf,
    const int* __restrict__ ws_i, const int* __restrict__ token_id,
    unsigned short* __restrict__ act)
{
    int e = blockIdx.z;
    int n_e = ws_i[e];
    int m0 = blockIdx.y * 128;
    if (m0 >= n_e) return;
    int base_e = ws_i[8 + e];
    int n0 = blockIdx.x * 128;
    __shared__ __align__(16) unsigned short sA[128 * LDK];
    __shared__ __align__(16) unsigned short sB1[128 * LDK];
    __shared__ __align__(16) unsigned short sB3[128 * LDK];
    int tid = threadIdx.x;
    int lane = tid & 63;
    int wv = tid >> 6;
    int wm = (wv >> 1) * 64;
    int wn = (wv & 1) * 64;
    int lr = lane & 15;
    int lq = lane >> 4;
    const float* W1 = w1 + (size_t)e * H_DIM * I_DIM;
    const float* W3 = w3 + (size_t)e * H_DIM * I_DIM;
    floatx4 zero4 = {0.f, 0.f, 0.f, 0.f};
    floatx4 acc1[16], acc3[16];
#pragma unroll
    for (int i = 0; i < 16; i++) { acc1[i] = zero4; acc3[i] = zero4; }
    int rowA0 = tid >> 2, kgA0 = tid & 3;
    int rowA1 = rowA0 + 64;
    int tA0 = (m0 + rowA0 < n_e) ? token_id[base_e + m0 + rowA0] : -1;
    int tA1 = (m0 + rowA1 < n_e) ? token_id[base_e + m0 + rowA1] : -1;
    int nB = tid & 127, kgB = tid >> 7;
    for (int k0 = 0; k0 < H_DIM; k0 += 32) {
        uint4 v0 = {0, 0, 0, 0}, v1 = {0, 0, 0, 0};
        if (tA0 >= 0) v0 = *(const uint4*)(hbf + (size_t)tA0 * H_DIM + k0 + kgA0 * 8);
        if (tA1 >= 0) v1 = *(const uint4*)(hbf + (size_t)tA1 * H_DIM + k0 + kgA0 * 8);
        *(uint4*)(sA + rowA0 * LDK + kgA0 * 8) = v0;
        *(uint4*)(sA + rowA1 * LDK + kgA0 * 8) = v1;
#pragma unroll
        for (int i = 0; i < 2; i++) {
            int kg = kgB + i * 2;
            const float* p1 = W1 + (size_t)(k0 + kg * 8) * I_DIM + (n0 + nB);
            const float* p3 = W3 + (size_t)(k0 + kg * 8) * I_DIM + (n0 + nB);
            short8 b1v, b3v;
#pragma unroll
            for (int j = 0; j < 8; j++) {
                b1v[j] = (short)f2bf(p1[(size_t)j * I_DIM]);
                b3v[j] = (short)f2bf(p3[(size_t)j * I_DIM]);
            }
            *(short8*)(sB1 + nB * LDK + kg * 8) = b1v;
            *(short8*)(sB3 + nB * LDK + kg * 8) = b3v;
        }
        __syncthreads();
        short8 af[4];
#pragma unroll
        for (int mi = 0; mi < 4; mi++)
            af[mi] = *(const short8*)(sA + (wm + mi * 16 + lr) * LDK + lq * 8);
#pragma unroll
        for (int ni = 0; ni < 4; ni++) {
            short8 b1 = *(const short8*)(sB1 + (wn + ni * 16 + lr) * LDK + lq * 8);
            short8 b3 = *(const short8*)(sB3 + (wn + ni * 16 + lr) * LDK + lq * 8);
#pragma unroll
            for (int mi = 0; mi < 4; mi++) {
                acc1[mi * 4 + ni] = __builtin_amdgcn_mfma_f32_16x16x32_bf16(af[mi], b1, acc1[mi * 4 + ni], 0, 0, 0);
                acc3[mi * 4 + ni] = __builtin_amdgcn_mfma_f32_16x16x32_bf16(af[mi], b3, acc3[mi * 4 + ni], 0, 0, 0);
            }
        }
        __syncthreads();
    }
#pragma unroll
    for (int mi = 0; mi < 4; mi++) {
#pragma unroll
        for (int r = 0; r < 4; r++) {
            int gm = m0 + wm + mi * 16 + lq * 4 + r;
            if (gm < n_e) {
                size_t rowoff = (size_t)(base_e + gm) * I_DIM + n0 + wn;
#pragma unroll
                for (int ni = 0; ni < 4; ni++) {
                    float x = acc1[mi * 4 + ni][r];
                    float y = acc3[mi * 4 + ni][r];
                    float s = x / (1.f + __expf(-x)) * y;
                    act[rowoff + ni * 16 + lr] = f2bf(s);
                }
            }
        }
    }
}

__global__ __launch_bounds__(256) void down_fb(
    const float* __restrict__ w2,
    const unsigned short* __restrict__ act,
    const int* __restrict__ ws_i, const int* __restrict__ token_id,
    const float* __restrict__ tok_w,
    float* __restrict__ out)
{
    int e = blockIdx.z;
    int n_e = ws_i[e];
    int m0 = blockIdx.y * 128;
    if (m0 >= n_e) return;
    int base_e = ws_i[8 + e];
    int n0 = blockIdx.x * 128;
    __shared__ __align__(16) unsigned short sA[128 * LDK];
    __shared__ __align__(16) unsigned short sB[128 * LDK];
    int tid = threadIdx.x;
    int lane = tid & 63;
    int wv = tid >> 6;
    int wm = (wv >> 1) * 64;
    int wn = (wv & 1) * 64;
    int lr = lane & 15;
    int lq = lane >> 4;
    const float* W2 = w2 + (size_t)e * I_DIM * H_DIM;
    floatx4 zero4 = {0.f, 0.f, 0.f, 0.f};
    floatx4 acc[16];
#pragma unroll
    for (int i = 0; i < 16; i++) acc[i] = zero4;
    int rowA0 = tid >> 2, kgA0 = tid & 3;
    int rowA1 = rowA0 + 64;
    bool vA0 = (m0 + rowA0 < n_e), vA1 = (m0 + rowA1 < n_e);
    const unsigned short* arow0 = act + (size_t)(base_e + m0 + rowA0) * I_DIM + kgA0 * 8;
    const unsigned short* arow1 = act + (size_t)(base_e + m0 + rowA1) * I_DIM + kgA0 * 8;
    int nB = tid & 127, kgB = tid >> 7;
    for (int k0 = 0; k0 < I_DIM; k0 += 32) {
        uint4 v0 = {0, 0, 0, 0}, v1 = {0, 0, 0, 0};
        if (vA0) v0 = *(const uint4*)(arow0 + k0);
        if (vA1) v1 = *(const uint4*)(arow1 + k0);
        *(uint4*)(sA + rowA0 * LDK + kgA0 * 8) = v0;
        *(uint4*)(sA + rowA1 * LDK + kgA0 * 8) = v1;
#pragma unroll
        for (int i = 0; i < 2; i++) {
            int kg = kgB + i * 2;
            const float* p = W2 + (size_t)(k0 + kg * 8) * H_DIM + (n0 + nB);
            short8 bv;
#pragma unroll
            for (int j = 0; j < 8; j++) bv[j] = (short)f2bf(p[(size_t)j * H_DIM]);
            *(short8*)(sB + nB * LDK + kg * 8) = bv;
        }
        __syncthreads();
        short8 af[4];
#pragma unroll
        for (int mi = 0; mi < 4; mi++)
            af[mi] = *(const short8*)(sA + (wm + mi * 16 + lr) * LDK + lq * 8);
#pragma unroll
        for (int ni = 0; ni < 4; ni++) {
            short8 b = *(const short8*)(sB + (wn + ni * 16 + lr) * LDK + lq * 8);
#pragma unroll
            for (int mi = 0; mi < 4; mi++)
                acc[mi * 4 + ni] = __builtin_amdgcn_mfma_f32_16x16x32_bf16(af[mi], b, acc[mi * 4 + ni], 0, 0, 0);
        }
        __syncthreads();
    }
#pragma unroll
    for (int mi = 0; mi < 4; mi++) {
#pragma unroll
        for (int r = 0; r < 4; r++) {
            int gm = m0 + wm + mi * 16 + lq * 4 + r;
            if (gm < n_e) {
                int gs = base_e + gm;
                int t = token_id[gs];
                float wgt = tok_w[gs];
                float* orow = out + (size_t)t * H_DIM + n0 + wn;
#pragma unroll
                for (int ni = 0; ni < 4; ni++)
                    atomicAdd(orow + ni * 16 + lr, wgt * acc[mi * 4 + ni][r]);
            }
        }
    }
}

extern "C" void kernel_launch(void* const* d_in, const int* in_sizes, int n_in,
                              void* d_out, int out_size, void* d_ws, size_t ws_size,
                              hipStream_t stream) {
    const float* hidden = (const float*)d_in[0];
    const float* gate   = (const float*)d_in[1];
    const float* w1     = (const float*)d_in[2];
    const float* w3     = (const float*)d_in[3];
    const float* w2     = (const float*)d_in[4];
    float* out_final  = (float*)d_out;
    float* out_logits = out_final + (size_t)T_TOK * H_DIM;

    // common workspace prefix
    char* wsb = (char*)d_ws;
    int*   ws_i     = (int*)wsb;                              // counts[8], base[8], cursor[8]
    int*   e0a      = (int*)(wsb + 256);                      // [T]
    int*   e1a      = e0a + T_TOK;
    float* p0a      = (float*)(e1a + T_TOK);
    float* p1a      = p0a + T_TOK;
    int*   token_id = (int*)(p1a + T_TOK);                    // [2T]
    float* tok_w    = (float*)(token_id + 2 * T_TOK);         // [2T]
    unsigned short* hbf = (unsigned short*)(tok_w + 2 * T_TOK);   // [T*H] bf16
    unsigned short* act = hbf + (size_t)T_TOK * H_DIM;            // [2T*I] bf16
    unsigned short* w1t = act + (size_t)2 * T_TOK * I_DIM;        // [E*I*H] bf16
    unsigned short* w3t = w1t + (size_t)E_NUM * I_DIM * H_DIM;
    unsigned short* w2t = w3t + (size_t)E_NUM * I_DIM * H_DIM;

    const size_t NEED_PRIMARY =
        (size_t)(256 + 4 * 16384 + 2 * 32768) +
        (size_t)T_TOK * H_DIM * 2 +            // hbf
        (size_t)2 * T_TOK * I_DIM * 2 +        // act
        (size_t)3 * E_NUM * I_DIM * H_DIM * 2; // w1t,w3t,w2t

    hipMemsetAsync(d_out, 0, (size_t)T_TOK * H_DIM * sizeof(float), stream);
    hipMemsetAsync(d_ws, 0, 256, stream);

    router_kernel<<<T_TOK / 4, 256, 0, stream>>>(hidden, gate, out_logits, ws_i, e0a, e1a, p0a, p1a);
    prefix_kernel<<<1, 64, 0, stream>>>(ws_i);
    assign_cvt_kernel<<<(T_TOK * H_DIM / 8) / 256, 256, 0, stream>>>(
        hidden, ws_i, e0a, e1a, p0a, p1a, token_id, tok_w, hbf);

    if (ws_size >= NEED_PRIMARY) {
        // transpose-convert weights to bf16 [n][k]
        cvt_t_kernel<<<dim3(I_DIM / 64, H_DIM / 64, E_NUM), 256, 0, stream>>>(w1, w1t, H_DIM, I_DIM);
        cvt_t_kernel<<<dim3(I_DIM / 64, H_DIM / 64, E_NUM), 256, 0, stream>>>(w3, w3t, H_DIM, I_DIM);
        cvt_t_kernel<<<dim3(H_DIM / 64, I_DIM / 64, E_NUM), 256, 0, stream>>>(w2, w2t, I_DIM, H_DIM);
        up_kernel<<<dim3(I_DIM / 64, T_TOK / 128, E_NUM), 256, 0, stream>>>(
            w1t, w3t, hbf, ws_i, token_id, act);
        down_kernel<<<dim3(H_DIM / 128, T_TOK / 128, E_NUM), 256, 0, stream>>>(
            w2t, act, ws_i, token_id, tok_w, out_final);
    } else {
        up_fb<<<dim3(I_DIM / 128, T_TOK / 128, E_NUM), 256, 0, stream>>>(
            w1, w3, hbf, ws_i, token_id, act);
        down_fb<<<dim3(H_DIM / 128, T_TOK / 128, E_NUM), 256, 0, stream>>>(
            w2, act, ws_i, token_id, tok_w, out_final);
    }
}